// Round 6
// baseline (5118.195 us; speedup 1.0000x reference)
//
#include <hip/hip_runtime.h>

static constexpr int TT = 512, BBATCH = 64, DD = 256, HH = 1024, OOUT = 64;

typedef float f32x4 __attribute__((ext_vector_type(4)));
typedef short bfrag __attribute__((ext_vector_type(8)));

__device__ __forceinline__ float sigm(float x) { return 1.0f / (1.0f + __expf(-x)); }
__device__ __forceinline__ float tanh_fast(float x) {
    return 1.0f - 2.0f / (__expf(2.0f * x) + 1.0f);
}
__device__ __forceinline__ unsigned short f2bf(float f) {
    unsigned int u = __builtin_bit_cast(unsigned int, f);
    u += 0x7FFFu + ((u >> 16) & 1u);
    return (unsigned short)(u >> 16);
}

struct Params {
    const float *x, *W_real, *W_imag, *U_w, *U_b, *W_tau_w, *W_tau_b,
                *mask_real, *mask_imag, *tau_bias, *b_real, *b_imag, *out_w, *out_b;
    float* out;             // [T][B][O]
    unsigned short* act;    // ws: [8 grp][3 mat][2 par][8 b][1024 h] bf16 (xcd) / [3][2][64][1024] (llc)
    float* zread;           // ws: [8 grp][2 par][8 b][1024 h] f32     / [2][64][1024] (llc)
    unsigned int* ctr;      // ws: [0]=global barrier; +128B+grp*128B = group counters
    unsigned int* xccmap;   // ws: [256] published XCC ids
    unsigned short* uslab;  // ws: bf16 frag-ordered U    [32 slot][2 tile][64 lane][8 ks][8]
    unsigned short* wtau;   // ws: bf16 frag-ordered Wtau [32 slot][2 tile][2 kh][64 lane][16 ks][8]
    int haveWT;
};

// L2-coherent load (bypass L1 only): for XCD-local cross-WG data.
#define LDL(v_, p_, o_) asm volatile("global_load_dwordx4 %0, %1, off offset:" #o_ " sc0" \
                                     : "=v"(v_) : "v"(p_))
// Device-coherent load (bypass L1+L2): for cross-XCD data.
#define LDC(v_, p_, o_) asm volatile("global_load_dwordx4 %0, %1, off offset:" #o_ " sc0 sc1" \
                                     : "=v"(v_) : "v"(p_))
// Plain cached load for read-only slabs.
#define LDP(v_, p_, o_) asm volatile("global_load_dwordx4 %0, %1, off offset:" #o_ \
                                     : "=v"(v_) : "v"(p_))
#define WAITV(n_) do { asm volatile("s_waitcnt vmcnt(" #n_ ")" ::: "memory"); \
                       __builtin_amdgcn_sched_barrier(0); } while (0)
#define MFMA(a_, b_, c_) __builtin_amdgcn_mfma_f32_16x16x32_bf16(a_, b_, c_, 0, 0, 0)
#define STC(p_, v_) __hip_atomic_store((p_), (v_), __ATOMIC_RELAXED, __HIP_MEMORY_SCOPE_AGENT)

#define ISSUE_A16(MACRO_) do { \
    MACRO_(a0,ap,0);   MACRO_(a1,ap,64);  MACRO_(a2,ap,128);  MACRO_(a3,ap,192);  \
    MACRO_(a4,ap,256); MACRO_(a5,ap,320); MACRO_(a6,ap,384);  MACRO_(a7,ap,448);  \
    MACRO_(a8,ap,512); MACRO_(a9,ap,576); MACRO_(a10,ap,640); MACRO_(a11,ap,704); \
    MACRO_(a12,ap,768);MACRO_(a13,ap,832);MACRO_(a14,ap,896); MACRO_(a15,ap,960); } while (0)

// ============================ XCD-local kernel =============================
// 256 WGs x 512 thr, 1 WG/CU (LDS 138240). 8 groups of 32 WGs by blockIdx%8
// (count-exact barriers). Runtime check: if a group's 32 WGs share one XCC,
// it runs L2-local coherence (plain stores + sc0 loads + L2 barrier); else
// it falls back to the proven LLC (sc0sc1/AGENT) protocol. Always correct.
__global__ void __launch_bounds__(512, 2) lnn_xcd(Params p) {
    extern __shared__ char smem[];
    unsigned short* Wlds = (unsigned short*)smem;     // [2][32][1024] bf16, swizzled
    float* EX = (float*)(smem + 131072);              // [14][128] f32 partials
    __shared__ int sh_mode;

    const int tid = threadIdx.x, wave = tid >> 6, lane = tid & 63;
    const int g = blockIdx.x, grp = g & 7, slot = g >> 3;
    const int h0 = slot * 32, b0g = grp * 8;
    const int gact = grp * 49152;   // shorts
    const int gz = grp * 16384;     // floats

    // ---- stage Wr, Wi (mask folded) into LDS, XOR-swizzled 16B granules ----
    for (int i = tid; i < 2 * 32 * 1024; i += 512) {
        const int mat = i >> 15, r = (i >> 10) & 31, k = i & 1023;
        const int idx = (h0 + r) * HH + k;
        const float w = (mat == 0) ? p.W_real[idx] * sigm(p.mask_real[idx])
                                   : p.W_imag[idx] * sigm(p.mask_imag[idx]);
        const int gk = (k >> 3) ^ (r & 7);
        Wlds[(mat * 32 + r) * 1024 + gk * 8 + (k & 7)] = f2bf(w);
    }
    // ---- publish physical XCC id ----
    if (tid == 0) {
        unsigned int x;
        asm volatile("s_getreg_b32 %0, hwreg(HW_REG_XCC_ID)" : "=s"(x));
        p.xccmap[g] = x & 15u;
    }
    // ---- stage Wtau / U bf16 frag slabs (one writer group) ----
    if (p.haveWT && grp == 0) {
        for (int e = tid; e < 4096; e += 512) {   // [tile][kh][lane][ks]
            const int ks = e & 15, l = (e >> 4) & 63, kh = (e >> 10) & 1, tle = e >> 11;
            const int m = l & 15, kb = l >> 4;
            const float* s = p.W_tau_w + (size_t)(h0 + tle * 16 + m) * HH
                             + kh * 512 + ks * 32 + kb * 8;
            unsigned short* d = p.wtau + (size_t)slot * 32768 + e * 8;
            #pragma unroll
            for (int j = 0; j < 8; ++j) d[j] = f2bf(s[j]);
        }
        for (int e = tid; e < 1024; e += 512) {   // [tile][lane][ks]
            const int ks = e & 7, l = (e >> 3) & 63, tle = e >> 9;
            const int m = l & 15, kb = l >> 4;
            const float* s = p.U_w + (size_t)(h0 + tle * 16 + m) * DD + ks * 32 + kb * 8;
            unsigned short* d = p.uslab + (size_t)slot * 8192 + e * 8;
            #pragma unroll
            for (int j = 0; j < 8; ++j) d[j] = f2bf(s[j]);
        }
    }
    __syncthreads();
    if (tid == 0) __threadfence();   // one-time flush: slabs + xccmap -> LLC
    __syncthreads();
    // ---- global barrier (LLC) + mode decision ----
    if (tid == 0) {
        __hip_atomic_fetch_add(p.ctr, 1u, __ATOMIC_RELAXED, __HIP_MEMORY_SCOPE_AGENT);
        int guard = 1 << 18;
        while (__hip_atomic_load(p.ctr, __ATOMIC_RELAXED, __HIP_MEMORY_SCOPE_AGENT) < 256u
               && --guard)
            __builtin_amdgcn_s_sleep(1);
        unsigned int x0 = 0; int ok = 1;
        for (int j = 0; j < 32; ++j) {
            const unsigned int* q = p.xccmap + (grp + 8 * j);
            unsigned int v;
            asm volatile("global_load_dword %0, %1, off sc0 sc1\n\ts_waitcnt vmcnt(0)"
                         : "=v"(v) : "v"(q) : "memory");
            if (j == 0) x0 = v; else ok &= (v == x0);
        }
        sh_mode = ok;
    }
    __syncthreads();
    const int lm = sh_mode;

    // ---- per-thread state + parity-1 act init ----
    float zr = 0.f, zi = 0.f, cbr = 0.f, cbi = 0.f, cwtb = 0.f, ctb = 0.f, cub = 0.f;
    int myoff = 0;
    if (tid < 256) {
        const int myb = tid >> 5, mh = tid & 31, hh = h0 + mh;
        myoff = myb * 1024 + hh;
        cbr = p.b_real[hh]; cbi = p.b_imag[hh];
        cwtb = p.W_tau_b[hh]; ctb = p.tau_bias[hh]; cub = p.U_b[hh];
        if (lm) {
            p.act[gact + 1 * 8192 + myoff] = 0;
            p.act[gact + 3 * 8192 + myoff] = 0;
            p.act[gact + 5 * 8192 + myoff] = 0;
        } else {
            STC(p.act + gact + 1 * 8192 + myoff, (unsigned short)0);
            STC(p.act + gact + 3 * 8192 + myoff, (unsigned short)0);
            STC(p.act + gact + 5 * 8192 + myoff, (unsigned short)0);
        }
    }

    unsigned int* bar = p.ctr + 32 + grp * 32;   // 128B-separated per-group lines
    auto gbar = [&](unsigned int gen) {
        __syncthreads();                          // drains vmcnt: stores visible
        if (tid == 0) {
            const unsigned int tgt = 32u * gen;
            if (lm) {
                asm volatile("global_atomic_add %0, %1, off" :: "v"(bar), "v"(1u) : "memory");
                unsigned int v; int guard = 1 << 18;
                do {
                    __builtin_amdgcn_s_sleep(1);
                    asm volatile("global_load_dword %0, %1, off sc0\n\ts_waitcnt vmcnt(0)"
                                 : "=v"(v) : "v"(bar) : "memory");
                } while (v < tgt && --guard);
            } else {
                __hip_atomic_fetch_add(bar, 1u, __ATOMIC_RELAXED, __HIP_MEMORY_SCOPE_AGENT);
                int guard = 1 << 18;
                while (__hip_atomic_load(bar, __ATOMIC_RELAXED, __HIP_MEMORY_SCOPE_AGENT) < tgt
                       && --guard)
                    __builtin_amdgcn_s_sleep(1);
            }
        }
        __syncthreads();
    };

    gbar(1);

    for (int t = 0; t <= TT; ++t) {
        const int rp = (t + 1) & 1;

        if (t < TT && wave < 4) {
            // waves 0-3: mats r/i (LDS weights), (mat, K-half), both 16-col tiles
            const int mat = wave >> 1, kh = wave & 1;
            const int m = lane & 15, kb = lane >> 4, sw = m & 7;
            const unsigned short* ap = p.act + gact + (mat * 2 + rp) * 8192
                                       + (m & 7) * 1024 + kh * 512 + kb * 8;
            bfrag a0,a1,a2,a3,a4,a5,a6,a7,a8,a9,a10,a11,a12,a13,a14,a15;
            if (lm) ISSUE_A16(LDL); else ISSUE_A16(LDC);
            f32x4 acc0 = {0.f,0.f,0.f,0.f}, acc1 = {0.f,0.f,0.f,0.f};
            const unsigned short* w0 = Wlds + (mat * 32 + m) * 1024;
            const unsigned short* w1 = w0 + 16 * 1024;
            #define ST2(ks_, av_) { const int gi = ((kh * 16 + (ks_)) * 4 + kb) ^ sw; \
                acc0 = MFMA(av_, *(const bfrag*)(w0 + (gi << 3)), acc0); \
                acc1 = MFMA(av_, *(const bfrag*)(w1 + (gi << 3)), acc1); }
            WAITV(8);
            ST2(0,a0) ST2(1,a1) ST2(2,a2) ST2(3,a3)
            ST2(4,a4) ST2(5,a5) ST2(6,a6) ST2(7,a7)
            WAITV(0);
            ST2(8,a8) ST2(9,a9) ST2(10,a10) ST2(11,a11)
            ST2(12,a12) ST2(13,a13) ST2(14,a14) ST2(15,a15)
            #undef ST2
            if (kb < 2) {
                float* e0 = EX + ((mat * 2 + kh) * 2) * 128;
                #pragma unroll
                for (int q = 0; q < 4; ++q) {
                    e0[(kb * 4 + q) * 16 + m] = acc0[q];
                    e0[128 + (kb * 4 + q) * 16 + m] = acc1[q];
                }
            }
        } else if (t < TT && wave < 6) {
            // waves 4-5: tau matvec, weights from bf16 ws slab (or fp32 stream)
            const int kh = wave & 1;
            const int m = lane & 15, kb = lane >> 4;
            const unsigned short* ap = p.act + gact + (4 + rp) * 8192
                                       + (m & 7) * 1024 + kh * 512 + kb * 8;
            bfrag a0,a1,a2,a3,a4,a5,a6,a7,a8,a9,a10,a11,a12,a13,a14,a15;
            if (lm) ISSUE_A16(LDL); else ISSUE_A16(LDC);
            f32x4 acc0 = {0.f,0.f,0.f,0.f}, acc1 = {0.f,0.f,0.f,0.f};
            if (p.haveWT) {
                const unsigned short* wb = p.wtau + (size_t)slot * 32768;
                const unsigned short* bp0 = wb + ((size_t)((0 * 2 + kh) * 64 + lane)) * 128;
                const unsigned short* bp1 = wb + ((size_t)((1 * 2 + kh) * 64 + lane)) * 128;
                bfrag b0,b1,b2,b3,b4,b5,b6,b7,b8,b9,b10,b11,b12,b13,b14,b15;
                #define ISSUE_B16(bp_) do { \
                    LDP(b0,bp_,0);   LDP(b1,bp_,16);  LDP(b2,bp_,32);   LDP(b3,bp_,48);  \
                    LDP(b4,bp_,64);  LDP(b5,bp_,80);  LDP(b6,bp_,96);   LDP(b7,bp_,112); \
                    LDP(b8,bp_,128); LDP(b9,bp_,144); LDP(b10,bp_,160); LDP(b11,bp_,176);\
                    LDP(b12,bp_,192);LDP(b13,bp_,208);LDP(b14,bp_,224); LDP(b15,bp_,240);} while (0)
                #define MF16(acc_) { \
                    acc_ = MFMA(a0,b0,acc_);   acc_ = MFMA(a1,b1,acc_); \
                    acc_ = MFMA(a2,b2,acc_);   acc_ = MFMA(a3,b3,acc_); \
                    acc_ = MFMA(a4,b4,acc_);   acc_ = MFMA(a5,b5,acc_); \
                    acc_ = MFMA(a6,b6,acc_);   acc_ = MFMA(a7,b7,acc_); \
                    acc_ = MFMA(a8,b8,acc_);   acc_ = MFMA(a9,b9,acc_); \
                    acc_ = MFMA(a10,b10,acc_); acc_ = MFMA(a11,b11,acc_); \
                    acc_ = MFMA(a12,b12,acc_); acc_ = MFMA(a13,b13,acc_); \
                    acc_ = MFMA(a14,b14,acc_); acc_ = MFMA(a15,b15,acc_); }
                ISSUE_B16(bp0);
                WAITV(0);
                MF16(acc0);
                ISSUE_B16(bp1);
                WAITV(0);
                MF16(acc1);
                #undef MF16
                #undef ISSUE_B16
            } else {
                WAITV(0);
                const float* q0 = p.W_tau_w + (size_t)(h0 + m) * HH + kh * 512 + kb * 8;
                const float* q1 = q0 + 16 * HH;
                #define MFS(ks_, av_) { \
                    const f32x4 u0 = *(const f32x4*)(q0 + (ks_) * 32); \
                    const f32x4 u1 = *(const f32x4*)(q0 + (ks_) * 32 + 4); \
                    const f32x4 v0 = *(const f32x4*)(q1 + (ks_) * 32); \
                    const f32x4 v1 = *(const f32x4*)(q1 + (ks_) * 32 + 4); \
                    bfrag bb0, bb1; \
                    bb0[0]=(short)f2bf(u0[0]); bb0[1]=(short)f2bf(u0[1]); \
                    bb0[2]=(short)f2bf(u0[2]); bb0[3]=(short)f2bf(u0[3]); \
                    bb0[4]=(short)f2bf(u1[0]); bb0[5]=(short)f2bf(u1[1]); \
                    bb0[6]=(short)f2bf(u1[2]); bb0[7]=(short)f2bf(u1[3]); \
                    bb1[0]=(short)f2bf(v0[0]); bb1[1]=(short)f2bf(v0[1]); \
                    bb1[2]=(short)f2bf(v0[2]); bb1[3]=(short)f2bf(v0[3]); \
                    bb1[4]=(short)f2bf(v1[0]); bb1[5]=(short)f2bf(v1[1]); \
                    bb1[6]=(short)f2bf(v1[2]); bb1[7]=(short)f2bf(v1[3]); \
                    acc0 = MFMA(av_, bb0, acc0); acc1 = MFMA(av_, bb1, acc1); }
                MFS(0,a0) MFS(1,a1) MFS(2,a2) MFS(3,a3)
                MFS(4,a4) MFS(5,a5) MFS(6,a6) MFS(7,a7)
                MFS(8,a8) MFS(9,a9) MFS(10,a10) MFS(11,a11)
                MFS(12,a12) MFS(13,a13) MFS(14,a14) MFS(15,a15)
                #undef MFS
            }
            if (kb < 2) {
                float* e0 = EX + ((4 + kh) * 2) * 128;
                #pragma unroll
                for (int q = 0; q < 4; ++q) {
                    e0[(kb * 4 + q) * 16 + m] = acc0[q];
                    e0[128 + (kb * 4 + q) * 16 + m] = acc1[q];
                }
            }
        } else if (wave == 6 && t < TT) {
            // wave 6: ux = x[t] @ U_w.T (K=256), both tiles; all compiler loads
            const int m = lane & 15, kb = lane >> 4;
            const float* xrow = p.x + ((size_t)t * BBATCH + b0g + (m & 7)) * DD + kb * 8;
            f32x4 acc0 = {0.f,0.f,0.f,0.f}, acc1 = {0.f,0.f,0.f,0.f};
            if (p.haveWT) {
                const bfrag* u0 = (const bfrag*)(p.uslab + (size_t)slot * 8192) + lane * 8;
                const bfrag* u1 = u0 + 64 * 8;
                #pragma unroll
                for (int ks = 0; ks < 8; ++ks) {
                    const f32x4 x0 = *(const f32x4*)(xrow + ks * 32);
                    const f32x4 x1 = *(const f32x4*)(xrow + ks * 32 + 4);
                    bfrag a;
                    a[0]=(short)f2bf(x0[0]); a[1]=(short)f2bf(x0[1]);
                    a[2]=(short)f2bf(x0[2]); a[3]=(short)f2bf(x0[3]);
                    a[4]=(short)f2bf(x1[0]); a[5]=(short)f2bf(x1[1]);
                    a[6]=(short)f2bf(x1[2]); a[7]=(short)f2bf(x1[3]);
                    acc0 = MFMA(a, u0[ks], acc0);
                    acc1 = MFMA(a, u1[ks], acc1);
                }
            } else {
                const float* q0 = p.U_w + (size_t)(h0 + m) * DD + kb * 8;
                const float* q1 = q0 + 16 * DD;
                #pragma unroll
                for (int ks = 0; ks < 8; ++ks) {
                    const f32x4 x0 = *(const f32x4*)(xrow + ks * 32);
                    const f32x4 x1 = *(const f32x4*)(xrow + ks * 32 + 4);
                    const f32x4 u0 = *(const f32x4*)(q0 + ks * 32);
                    const f32x4 u1 = *(const f32x4*)(q0 + ks * 32 + 4);
                    const f32x4 v0 = *(const f32x4*)(q1 + ks * 32);
                    const f32x4 v1 = *(const f32x4*)(q1 + ks * 32 + 4);
                    bfrag a, bb0, bb1;
                    a[0]=(short)f2bf(x0[0]); a[1]=(short)f2bf(x0[1]);
                    a[2]=(short)f2bf(x0[2]); a[3]=(short)f2bf(x0[3]);
                    a[4]=(short)f2bf(x1[0]); a[5]=(short)f2bf(x1[1]);
                    a[6]=(short)f2bf(x1[2]); a[7]=(short)f2bf(x1[3]);
                    bb0[0]=(short)f2bf(u0[0]); bb0[1]=(short)f2bf(u0[1]);
                    bb0[2]=(short)f2bf(u0[2]); bb0[3]=(short)f2bf(u0[3]);
                    bb0[4]=(short)f2bf(u1[0]); bb0[5]=(short)f2bf(u1[1]);
                    bb0[6]=(short)f2bf(u1[2]); bb0[7]=(short)f2bf(u1[3]);
                    bb1[0]=(short)f2bf(v0[0]); bb1[1]=(short)f2bf(v0[1]);
                    bb1[2]=(short)f2bf(v0[2]); bb1[3]=(short)f2bf(v0[3]);
                    bb1[4]=(short)f2bf(v1[0]); bb1[5]=(short)f2bf(v1[1]);
                    bb1[6]=(short)f2bf(v1[2]); bb1[7]=(short)f2bf(v1[3]);
                    acc0 = MFMA(a, bb0, acc0);
                    acc1 = MFMA(a, bb1, acc1);
                }
            }
            if (kb < 2) {
                #pragma unroll
                for (int q = 0; q < 4; ++q) {
                    EX[12 * 128 + (kb * 4 + q) * 16 + m] = acc0[q];
                    EX[13 * 128 + (kb * 4 + q) * 16 + m] = acc1[q];
                }
            }
        } else if (wave == 7 && t >= 1) {
            // wave 7: exact fp32 readout y[t-1][b0g+b][slot*2 + {0,1}]
            const int b = lane >> 3, kc = lane & 7, o0 = slot * 2;
            const float* zp = p.zread + gz + ((t - 1) & 1) * 8192 + b * 1024 + kc * 128;
            const float* w0 = p.out_w + (size_t)o0 * HH + kc * 128;
            const float* w1 = w0 + HH;
            float s0 = 0.f, s1 = 0.f;
            #pragma unroll
            for (int hf = 0; hf < 2; ++hf) {
                const float* zq = zp + hf * 64;
                f32x4 z0,z1,z2,z3,z4,z5,z6,z7,z8,z9,z10,z11,z12,z13,z14,z15;
                if (lm) {
                    LDL(z0,zq,0);    LDL(z1,zq,16);   LDL(z2,zq,32);   LDL(z3,zq,48);
                    LDL(z4,zq,64);   LDL(z5,zq,80);   LDL(z6,zq,96);   LDL(z7,zq,112);
                    LDL(z8,zq,128);  LDL(z9,zq,144);  LDL(z10,zq,160); LDL(z11,zq,176);
                    LDL(z12,zq,192); LDL(z13,zq,208); LDL(z14,zq,224); LDL(z15,zq,240);
                } else {
                    LDC(z0,zq,0);    LDC(z1,zq,16);   LDC(z2,zq,32);   LDC(z3,zq,48);
                    LDC(z4,zq,64);   LDC(z5,zq,80);   LDC(z6,zq,96);   LDC(z7,zq,112);
                    LDC(z8,zq,128);  LDC(z9,zq,144);  LDC(z10,zq,160); LDC(z11,zq,176);
                    LDC(z12,zq,192); LDC(z13,zq,208); LDC(z14,zq,224); LDC(z15,zq,240);
                }
                WAITV(0);
                const f32x4* a0 = (const f32x4*)(w0 + hf * 64);
                const f32x4* a1 = (const f32x4*)(w1 + hf * 64);
                #define DOT(zi_, i_) { \
                    s0 += zi_[0]*a0[i_][0]+zi_[1]*a0[i_][1]+zi_[2]*a0[i_][2]+zi_[3]*a0[i_][3]; \
                    s1 += zi_[0]*a1[i_][0]+zi_[1]*a1[i_][1]+zi_[2]*a1[i_][2]+zi_[3]*a1[i_][3]; }
                DOT(z0,0) DOT(z1,1) DOT(z2,2) DOT(z3,3) DOT(z4,4) DOT(z5,5) DOT(z6,6) DOT(z7,7)
                DOT(z8,8) DOT(z9,9) DOT(z10,10) DOT(z11,11) DOT(z12,12) DOT(z13,13) DOT(z14,14) DOT(z15,15)
                #undef DOT
            }
            s0 += __shfl_xor(s0, 1, 64); s1 += __shfl_xor(s1, 1, 64);
            s0 += __shfl_xor(s0, 2, 64); s1 += __shfl_xor(s1, 2, 64);
            s0 += __shfl_xor(s0, 4, 64); s1 += __shfl_xor(s1, 4, 64);
            if (kc == 0) {
                float2 y = { s0 + p.out_b[o0], s1 + p.out_b[o0 + 1] };
                *(float2*)(p.out + (size_t)(t - 1) * BBATCH * OOUT + (b0g + b) * OOUT + o0) = y;
            }
        }

        __syncthreads();

        if (t < TT && tid < 256) {
            const int mh = tid & 31, tle = mh >> 4, ii = (tid >> 5) * 16 + (mh & 15);
            const float mr = EX[(0 + tle) * 128 + ii] + EX[(2 + tle) * 128 + ii];
            const float mi = EX[(4 + tle) * 128 + ii] + EX[(6 + tle) * 128 + ii];
            const float mt = EX[(8 + tle) * 128 + ii] + EX[(10 + tle) * 128 + ii];
            const float ux = EX[(12 + tle) * 128 + ii] + cub;
            const float dr0 = -zr + mr + ux + cbr;
            const float di0 = -zi + mi + ux + cbi;
            float tau = sigm(mt + cwtb) + ctb;
            tau = fminf(fmaxf(tau, 0.01f), 1.0f) + 1e-6f;
            const float dzr = fminf(fmaxf(dr0 / tau, -10.f), 10.f);
            const float dzi = fminf(fmaxf(di0 / tau, -10.f), 10.f);
            zr = fminf(fmaxf(zr + 0.1f * dzr, -100.f), 100.f);
            zi = fminf(fmaxf(zi + 0.1f * dzi, -100.f), 100.f);
            const float ar = tanh_fast(zr), ai = tanh_fast(zi);
            const float zm = sqrtf(zr * zr + zi * zi + 1e-20f);
            const int wp2 = t & 1;
            if (lm) {
                p.act[gact + (0 + wp2) * 8192 + myoff] = f2bf(ar);
                p.act[gact + (2 + wp2) * 8192 + myoff] = f2bf(ai);
                p.act[gact + (4 + wp2) * 8192 + myoff] = f2bf(zm);
                p.zread[gz + wp2 * 8192 + myoff] = zr;
            } else {
                STC(p.act + gact + (0 + wp2) * 8192 + myoff, f2bf(ar));
                STC(p.act + gact + (2 + wp2) * 8192 + myoff, f2bf(ai));
                STC(p.act + gact + (4 + wp2) * 8192 + myoff, f2bf(zm));
                STC(p.zread + gz + wp2 * 8192 + myoff, zr);
            }
        }

        if (t < TT) gbar(t + 2);
    }
}

// ===================== proven round-5 LLC kernel (fallback) =====================
__global__ void __launch_bounds__(512, 2) lnn_llc(Params p) {
    extern __shared__ char smem[];
    unsigned short* Wlds = (unsigned short*)smem;
    unsigned short* Ulds = (unsigned short*)(smem + 3 * 16 * 1024 * 2);
    float* EX = (float*)(smem + 3 * 16 * 1024 * 2 + 16 * 256 * 2);

    const int tid = threadIdx.x;
    const int wave = tid >> 6, lane = tid & 63;
    const int g = blockIdx.x;
    const int grp = (g & 7) >> 1;
    const int slot = ((g >> 3) << 1) | (g & 1);
    const int h0 = slot * 16, b0 = grp * 16;
    const int ro_b0 = b0 + (slot & 3) * 4, ro_o0 = (slot >> 2) * 4;

    for (int i = tid; i < 3 * 16 * 1024; i += 512) {
        const int mat = i >> 14, r = (i >> 10) & 15, k = i & 1023;
        const int idx = (h0 + r) * HH + k;
        float w;
        if (mat == 0)      w = p.W_real[idx] * sigm(p.mask_real[idx]);
        else if (mat == 1) w = p.W_imag[idx] * sigm(p.mask_imag[idx]);
        else               w = p.W_tau_w[idx];
        const int gk = (k >> 3) ^ (r & 7);
        Wlds[(mat * 16 + r) * 1024 + gk * 8 + (k & 7)] = f2bf(w);
    }
    for (int i = tid; i < 16 * 256; i += 512) {
        const int r = i >> 8, k = i & 255;
        const int gk = (k >> 3) ^ (r & 7);
        Ulds[r * 256 + gk * 8 + (k & 7)] = f2bf(p.U_w[(h0 + r) * DD + k]);
    }

    float zr = 0.f, zi = 0.f, cbr = 0.f, cbi = 0.f, cwtb = 0.f, ctb = 0.f, cub = 0.f;
    int myoff = 0;
    if (tid < 256) {
        const int myb = b0 + (tid >> 4), myh = h0 + (tid & 15);
        myoff = myb * HH + myh;
        cbr = p.b_real[myh]; cbi = p.b_imag[myh];
        cwtb = p.W_tau_b[myh]; ctb = p.tau_bias[myh]; cub = p.U_b[myh];
        STC(p.act + (0 * 2 + 1) * BBATCH * HH + myoff, (unsigned short)0);
        STC(p.act + (1 * 2 + 1) * BBATCH * HH + myoff, (unsigned short)0);
        STC(p.act + (2 * 2 + 1) * BBATCH * HH + myoff, (unsigned short)0);
    }

    unsigned int* bar = p.ctr + 32 + grp * 32;
    auto group_barrier = [&](unsigned int gen) {
        __syncthreads();
        if (tid == 0) {
            __hip_atomic_fetch_add(bar, 1u, __ATOMIC_RELAXED, __HIP_MEMORY_SCOPE_AGENT);
            const unsigned int tgt = 64u * gen;
            int guard = 1 << 20;
            while (__hip_atomic_load(bar, __ATOMIC_RELAXED, __HIP_MEMORY_SCOPE_AGENT) < tgt
                   && --guard)
                __builtin_amdgcn_s_sleep(1);
        }
        __syncthreads();
    };

    group_barrier(1);

    for (int t = 0; t <= TT; ++t) {
        const int rp = (t + 1) & 1;
        const int wp2 = t & 1;

        if (t < TT && wave < 6) {
            const int mat = wave >> 1, half = wave & 1;
            const int m = lane & 15, kb = lane >> 4, sw = m & 7;
            const unsigned short* ap = p.act + (mat * 2 + rp) * BBATCH * HH
                                       + (b0 + m) * HH + half * 512 + kb * 8;
            bfrag a0,a1,a2,a3,a4,a5,a6,a7,a8,a9,a10,a11,a12,a13,a14,a15;
            ISSUE_A16(LDC);
            f32x4 acc = {0.f, 0.f, 0.f, 0.f};
            const unsigned short* wrow = Wlds + (mat * 16 + m) * 1024;
            #define STW(ks_, av_) acc = MFMA(av_, *(const bfrag*)(wrow + \
                ((((half << 6) + ((ks_) << 2) + kb) ^ sw) << 3)), acc);
            WAITV(8);
            STW(0,a0) STW(1,a1) STW(2,a2) STW(3,a3)
            STW(4,a4) STW(5,a5) STW(6,a6) STW(7,a7)
            WAITV(0);
            STW(8,a8) STW(9,a9) STW(10,a10) STW(11,a11)
            STW(12,a12) STW(13,a13) STW(14,a14) STW(15,a15)
            #undef STW
            #pragma unroll
            for (int q = 0; q < 4; ++q)
                EX[wave * 256 + (kb * 4 + q) * 16 + m] = acc[q];
        } else if (wave == 6 && t < TT) {
            const int m = lane & 15, kb = lane >> 4, sw = m & 7;
            const float* xrow = p.x + ((size_t)t * BBATCH + (b0 + m)) * DD;
            const unsigned short* urow = Ulds + m * 256;
            f32x4 acc = {0.f, 0.f, 0.f, 0.f};
            #pragma unroll
            for (int ks = 0; ks < 8; ++ks) {
                const int k = ks * 32 + kb * 8;
                const f32x4 x0 = *(const f32x4*)(xrow + k);
                const f32x4 x1 = *(const f32x4*)(xrow + k + 4);
                bfrag a;
                a[0]=(short)f2bf(x0[0]); a[1]=(short)f2bf(x0[1]);
                a[2]=(short)f2bf(x0[2]); a[3]=(short)f2bf(x0[3]);
                a[4]=(short)f2bf(x1[0]); a[5]=(short)f2bf(x1[1]);
                a[6]=(short)f2bf(x1[2]); a[7]=(short)f2bf(x1[3]);
                const bfrag b = *(const bfrag*)(urow + (((ks * 4 + kb) ^ sw) << 3));
                acc = MFMA(a, b, acc);
            }
            #pragma unroll
            for (int q = 0; q < 4; ++q)
                EX[6 * 256 + (kb * 4 + q) * 16 + m] = acc[q];
        } else if (wave == 7 && t >= 1) {
            const int r = lane & 15, kq = lane >> 4;
            const int bb = ro_b0 + (r >> 2), oo = ro_o0 + (r & 3);
            const float* zp = p.zread + ((t - 1) & 1) * BBATCH * HH + bb * HH + kq * 256;
            const float* owp = p.out_w + oo * HH + kq * 256;
            float acc = 0.f;
            #define RB(bt_) { \
                const float* zq = zp + (bt_) * 64; \
                f32x4 z0,z1,z2,z3,z4,z5,z6,z7,z8,z9,z10,z11,z12,z13,z14,z15; \
                LDC(z0,zq,0);    LDC(z1,zq,16);   LDC(z2,zq,32);   LDC(z3,zq,48); \
                LDC(z4,zq,64);   LDC(z5,zq,80);   LDC(z6,zq,96);   LDC(z7,zq,112); \
                LDC(z8,zq,128);  LDC(z9,zq,144);  LDC(z10,zq,160); LDC(z11,zq,176); \
                LDC(z12,zq,192); LDC(z13,zq,208); LDC(z14,zq,224); LDC(z15,zq,240); \
                WAITV(0); \
                const f32x4* wq = (const f32x4*)(owp + (bt_) * 64); \
                acc += z0[0]*wq[0][0]+z0[1]*wq[0][1]+z0[2]*wq[0][2]+z0[3]*wq[0][3]; \
                acc += z1[0]*wq[1][0]+z1[1]*wq[1][1]+z1[2]*wq[1][2]+z1[3]*wq[1][3]; \
                acc += z2[0]*wq[2][0]+z2[1]*wq[2][1]+z2[2]*wq[2][2]+z2[3]*wq[2][3]; \
                acc += z3[0]*wq[3][0]+z3[1]*wq[3][1]+z3[2]*wq[3][2]+z3[3]*wq[3][3]; \
                acc += z4[0]*wq[4][0]+z4[1]*wq[4][1]+z4[2]*wq[4][2]+z4[3]*wq[4][3]; \
                acc += z5[0]*wq[5][0]+z5[1]*wq[5][1]+z5[2]*wq[5][2]+z5[3]*wq[5][3]; \
                acc += z6[0]*wq[6][0]+z6[1]*wq[6][1]+z6[2]*wq[6][2]+z6[3]*wq[6][3]; \
                acc += z7[0]*wq[7][0]+z7[1]*wq[7][1]+z7[2]*wq[7][2]+z7[3]*wq[7][3]; \
                acc += z8[0]*wq[8][0]+z8[1]*wq[8][1]+z8[2]*wq[8][2]+z8[3]*wq[8][3]; \
                acc += z9[0]*wq[9][0]+z9[1]*wq[9][1]+z9[2]*wq[9][2]+z9[3]*wq[9][3]; \
                acc += z10[0]*wq[10][0]+z10[1]*wq[10][1]+z10[2]*wq[10][2]+z10[3]*wq[10][3]; \
                acc += z11[0]*wq[11][0]+z11[1]*wq[11][1]+z11[2]*wq[11][2]+z11[3]*wq[11][3]; \
                acc += z12[0]*wq[12][0]+z12[1]*wq[12][1]+z12[2]*wq[12][2]+z12[3]*wq[12][3]; \
                acc += z13[0]*wq[13][0]+z13[1]*wq[13][1]+z13[2]*wq[13][2]+z13[3]*wq[13][3]; \
                acc += z14[0]*wq[14][0]+z14[1]*wq[14][1]+z14[2]*wq[14][2]+z14[3]*wq[14][3]; \
                acc += z15[0]*wq[15][0]+z15[1]*wq[15][1]+z15[2]*wq[15][2]+z15[3]*wq[15][3]; }
            RB(0) RB(1) RB(2) RB(3)
            #undef RB
            acc += __shfl_xor(acc, 16, 64);
            acc += __shfl_xor(acc, 32, 64);
            if (kq == 0)
                p.out[(size_t)(t - 1) * BBATCH * OOUT + bb * OOUT + oo] = acc + p.out_b[oo];
        }

        __syncthreads();

        if (t < TT && tid < 256) {
            const float mr = EX[0 * 256 + tid] + EX[1 * 256 + tid];
            const float mi = EX[2 * 256 + tid] + EX[3 * 256 + tid];
            const float mt = EX[4 * 256 + tid] + EX[5 * 256 + tid];
            const float ux = EX[6 * 256 + tid] + cub;
            const float dr0 = -zr + mr + ux + cbr;
            const float di0 = -zi + mi + ux + cbi;
            float tau = sigm(mt + cwtb) + ctb;
            tau = fminf(fmaxf(tau, 0.01f), 1.0f) + 1e-6f;
            const float dzr = fminf(fmaxf(dr0 / tau, -10.f), 10.f);
            const float dzi = fminf(fmaxf(di0 / tau, -10.f), 10.f);
            zr = fminf(fmaxf(zr + 0.1f * dzr, -100.f), 100.f);
            zi = fminf(fmaxf(zi + 0.1f * dzi, -100.f), 100.f);
            const float ar = tanh_fast(zr), ai = tanh_fast(zi);
            const float zm = sqrtf(zr * zr + zi * zi + 1e-20f);
            STC(p.act + (0 * 2 + wp2) * BBATCH * HH + myoff, f2bf(ar));
            STC(p.act + (1 * 2 + wp2) * BBATCH * HH + myoff, f2bf(ai));
            STC(p.act + (2 * 2 + wp2) * BBATCH * HH + myoff, f2bf(zm));
            STC(p.zread + wp2 * BBATCH * HH + myoff, zr);
        }

        if (t < TT) group_barrier(t + 2);
    }
}

extern "C" void kernel_launch(void* const* d_in, const int* in_sizes, int n_in,
                              void* d_out, int out_size, void* d_ws, size_t ws_size,
                              hipStream_t stream) {
    Params p;
    p.x         = (const float*)d_in[0];
    p.W_real    = (const float*)d_in[1];
    p.W_imag    = (const float*)d_in[2];
    p.U_w       = (const float*)d_in[3];
    p.U_b       = (const float*)d_in[4];
    p.W_tau_w   = (const float*)d_in[5];
    p.W_tau_b   = (const float*)d_in[6];
    p.mask_real = (const float*)d_in[7];
    p.mask_imag = (const float*)d_in[8];
    p.tau_bias  = (const float*)d_in[9];
    p.b_real    = (const float*)d_in[10];
    p.b_imag    = (const float*)d_in[11];
    p.out_w     = (const float*)d_in[12];
    p.out_b     = (const float*)d_in[13];
    p.out    = (float*)d_out;
    p.act    = (unsigned short*)d_ws;                           // 786432 B
    p.zread  = (float*)((char*)d_ws + 786432);                  // 524288 B
    p.ctr    = (unsigned int*)((char*)d_ws + 1310720);          // 2048 B
    p.xccmap = (unsigned int*)((char*)d_ws + 1312768);          // 1024 B
    p.uslab  = (unsigned short*)((char*)d_ws + 1313792);        // 524288 B
    p.wtau   = (unsigned short*)((char*)d_ws + 1838080);        // 2097152 B
    p.haveWT = (ws_size >= (size_t)1838080 + 2097152) ? 1 : 0;  // 3935232 total

    hipMemsetAsync((char*)d_ws + 1310720, 0, 3072, stream);     // ctr + xccmap

    constexpr unsigned SMX = 131072 + 14 * 128 * 4;             // 138240
    constexpr unsigned SML = 3 * 16 * 1024 * 2 + 16 * 256 * 2 + 8 * 256 * 4; // 114688
    void* args[] = { &p };

    int nb = 0;
    hipError_t ea = hipFuncSetAttribute(reinterpret_cast<const void*>(lnn_xcd),
                                        hipFuncAttributeMaxDynamicSharedMemorySize, SMX);
    hipOccupancyMaxActiveBlocksPerMultiprocessor(&nb, reinterpret_cast<const void*>(lnn_xcd),
                                                 512, SMX);
    hipError_t el = hipErrorUnknown;
    if (ea == hipSuccess && nb >= 1)
        el = hipLaunchCooperativeKernel(reinterpret_cast<const void*>(lnn_xcd),
                                        dim3(256), dim3(512), args, SMX, stream);
    if (el != hipSuccess) {
        (void)hipGetLastError();
        hipFuncSetAttribute(reinterpret_cast<const void*>(lnn_llc),
                            hipFuncAttributeMaxDynamicSharedMemorySize, SML);
        hipLaunchCooperativeKernel(reinterpret_cast<const void*>(lnn_llc),
                                   dim3(256), dim3(512), args, SML, stream);
    }
}

// Round 8
// 5001.335 us; speedup vs baseline: 1.0234x; 1.0234x over previous
//
#include <hip/hip_runtime.h>

static constexpr int TT = 512, BBATCH = 64, DD = 256, HH = 1024, OOUT = 64;

typedef float f32x4 __attribute__((ext_vector_type(4)));
typedef short bfrag __attribute__((ext_vector_type(8)));

__device__ __forceinline__ float sigm(float x) { return 1.0f / (1.0f + __expf(-x)); }
__device__ __forceinline__ float tanh_fast(float x) {
    return 1.0f - 2.0f / (__expf(2.0f * x) + 1.0f);   // exact at clip bounds
}
// fp32 -> bf16 bits, round-to-nearest-even (finite inputs only)
__device__ __forceinline__ unsigned short f2bf(float f) {
    unsigned int u = __builtin_bit_cast(unsigned int, f);
    u += 0x7FFFu + ((u >> 16) & 1u);
    return (unsigned short)(u >> 16);
}

struct Params {
    const float *x, *W_real, *W_imag, *U_w, *U_b, *W_tau_w, *W_tau_b,
                *mask_real, *mask_imag, *tau_bias, *b_real, *b_imag, *out_w, *out_b;
    float* out;             // [T][B][O]
    unsigned short* act;    // ws: [3 mats][2 parity][B][H] bf16
    float* zread;           // ws: [2 parity][B][H] f32
    unsigned int* bar;      // ws: 4 group counters, 128B apart (memset to 0 per launch)
};

// Device-coherent load: bypass L1+L2, served at LLC (Infinity Cache).
#define LDC(v_, p_, o_) asm volatile("global_load_dwordx4 %0, %1, off offset:" #o_ " sc0 sc1" \
                                     : "=v"(v_) : "v"(p_))
#define WAITV(n_) do { asm volatile("s_waitcnt vmcnt(" #n_ ")" ::: "memory"); \
                       __builtin_amdgcn_sched_barrier(0); } while (0)
#define MFMA(a_, b_, c_) __builtin_amdgcn_mfma_f32_16x16x32_bf16(a_, b_, c_, 0, 0, 0)
// Device-coherent store (write-through, no local-L2 dirty allocate).
#define STC(p_, v_) __hip_atomic_store((p_), (v_), __ATOMIC_RELAXED, __HIP_MEMORY_SCOPE_AGENT)

// 256 WGs x 512 threads, 1 WG/CU (LDS 114688B), persistent, cooperative.
// 4 b-groups of 64 WGs (blockIdx-derived). Cross-WG state flows through LLC
// via sc0+sc1 accesses; zero threadfence. Round-8 delta vs validated round-5:
// wave-6 Ux(t+1) and wave-7 readout(t-1) execute INSIDE the barrier-wait
// window (split-phase), readout is 2-bank pipelined with counted vmcnt.
__global__ void __launch_bounds__(512, 2) lnn_fused(Params p) {
    extern __shared__ char smem[];
    unsigned short* Wlds = (unsigned short*)smem;                      // [3][16][1024] bf16, swizzled
    unsigned short* Ulds = (unsigned short*)(smem + 3 * 16 * 1024 * 2);// [16][256]  bf16, swizzled
    float* EX = (float*)(smem + 3 * 16 * 1024 * 2 + 16 * 256 * 2);     // [8][256] f32 partials

    const int tid = threadIdx.x;
    const int wave = tid >> 6, lane = tid & 63;
    const int g = blockIdx.x;
    const int grp = (g & 7) >> 1;                 // b-group 0..3 (64 WGs each)
    const int slot = ((g >> 3) << 1) | (g & 1);   // h-slot 0..63 within group
    const int h0 = slot * 16, b0 = grp * 16;
    const int ro_b0 = b0 + (slot & 3) * 4, ro_o0 = (slot >> 2) * 4;

    // ---- stage weights into LDS: fold sigmoid(mask), cvt bf16, XOR-swizzle 16B granules ----
    for (int i = tid; i < 3 * 16 * 1024; i += 512) {
        const int mat = i >> 14, r = (i >> 10) & 15, k = i & 1023;
        const int idx = (h0 + r) * HH + k;
        float w;
        if (mat == 0)      w = p.W_real[idx] * sigm(p.mask_real[idx]);
        else if (mat == 1) w = p.W_imag[idx] * sigm(p.mask_imag[idx]);
        else               w = p.W_tau_w[idx];
        const int gk = (k >> 3) ^ (r & 7);
        Wlds[(mat * 16 + r) * 1024 + gk * 8 + (k & 7)] = f2bf(w);
    }
    for (int i = tid; i < 16 * 256; i += 512) {
        const int r = i >> 8, k = i & 255;
        const int gk = (k >> 3) ^ (r & 7);
        Ulds[r * 256 + gk * 8 + (k & 7)] = f2bf(p.U_w[(h0 + r) * DD + k]);
    }

    // ---- per-thread recurrent state + constants (threads 0..255 own one (b,h)) ----
    float zr = 0.f, zi = 0.f, cbr = 0.f, cbi = 0.f, cwtb = 0.f, ctb = 0.f, cub = 0.f;
    int myoff = 0;
    if (tid < 256) {
        const int myb = b0 + (tid >> 4), myh = h0 + (tid & 15);
        myoff = myb * HH + myh;
        cbr = p.b_real[myh]; cbi = p.b_imag[myh];
        cwtb = p.W_tau_b[myh]; ctb = p.tau_bias[myh]; cub = p.U_b[myh];
        // init parity-1 activation buffers (read at t=0): z0 = 0 -> tanh=0, |z|~0
        STC(p.act + (0 * 2 + 1) * BBATCH * HH + myoff, (unsigned short)0);
        STC(p.act + (1 * 2 + 1) * BBATCH * HH + myoff, (unsigned short)0);
        STC(p.act + (2 * 2 + 1) * BBATCH * HH + myoff, (unsigned short)0);
    }

    unsigned int* bar = p.bar + grp * 32;  // 128B-separated counters
    auto arrive = [&]() {
        __hip_atomic_fetch_add(bar, 1u, __ATOMIC_RELAXED, __HIP_MEMORY_SCOPE_AGENT);
    };
    auto waitbar = [&](unsigned int tgt) {
        int guard = 1 << 20;               // bounded spin: never hang the harness
        while (__hip_atomic_load(bar, __ATOMIC_RELAXED, __HIP_MEMORY_SCOPE_AGENT) < tgt
               && --guard)
            __builtin_amdgcn_s_sleep(1);
    };

    // ---- overlap workers ----
    auto uxcomp = [&](int tx) {   // wave 6: Ux(x[tx]) -> EX section 6 + (tx&1)
        const int m = lane & 15, kb = lane >> 4, sw = m & 7;
        const float* xrow = p.x + ((size_t)tx * BBATCH + (b0 + m)) * DD;
        const unsigned short* urow = Ulds + m * 256;
        f32x4 acc = {0.f, 0.f, 0.f, 0.f};
        #pragma unroll
        for (int ks = 0; ks < 8; ++ks) {
            const int k = ks * 32 + kb * 8;
            const f32x4 x0 = *(const f32x4*)(xrow + k);
            const f32x4 x1 = *(const f32x4*)(xrow + k + 4);
            bfrag a;
            a[0]=(short)f2bf(x0[0]); a[1]=(short)f2bf(x0[1]);
            a[2]=(short)f2bf(x0[2]); a[3]=(short)f2bf(x0[3]);
            a[4]=(short)f2bf(x1[0]); a[5]=(short)f2bf(x1[1]);
            a[6]=(short)f2bf(x1[2]); a[7]=(short)f2bf(x1[3]);
            const bfrag b = *(const bfrag*)(urow + (((ks * 4 + kb) ^ sw) << 3));
            acc = MFMA(a, b, acc);
        }
        float* e = EX + (6 + (tx & 1)) * 256;
        #pragma unroll
        for (int q = 0; q < 4; ++q)
            e[(kb * 4 + q) * 16 + m] = acc[q];   // C/D: row=(lane>>4)*4+q, col=m
    };
    auto readout = [&](int ty) {  // wave 7: y[ty], 2-bank pipelined LLC reads
        const int r = lane & 15, kq = lane >> 4;
        const int bb = ro_b0 + (r >> 2), oo = ro_o0 + (r & 3);
        const float* zp = p.zread + (ty & 1) * BBATCH * HH + bb * HH + kq * 256;
        const float* owp = p.out_w + oo * HH + kq * 256;
        float acc = 0.f;
        f32x4 A0,A1,A2,A3,A4,A5,A6,A7,A8,A9,A10,A11,A12,A13,A14,A15;
        f32x4 B0,B1,B2,B3,B4,B5,B6,B7,B8,B9,B10,B11,B12,B13,B14,B15;
        #define ISSUE_BANK(P_, zq_) do { \
            LDC(P_##0,zq_,0);    LDC(P_##1,zq_,16);   LDC(P_##2,zq_,32);   LDC(P_##3,zq_,48);  \
            LDC(P_##4,zq_,64);   LDC(P_##5,zq_,80);   LDC(P_##6,zq_,96);   LDC(P_##7,zq_,112); \
            LDC(P_##8,zq_,128);  LDC(P_##9,zq_,144);  LDC(P_##10,zq_,160); LDC(P_##11,zq_,176);\
            LDC(P_##12,zq_,192); LDC(P_##13,zq_,208); LDC(P_##14,zq_,224); LDC(P_##15,zq_,240);} while (0)
        #define DOT_BANK(P_, wq_) do { const f32x4* wq = (const f32x4*)(wq_); \
            acc += P_##0[0]*wq[0][0]+P_##0[1]*wq[0][1]+P_##0[2]*wq[0][2]+P_##0[3]*wq[0][3]; \
            acc += P_##1[0]*wq[1][0]+P_##1[1]*wq[1][1]+P_##1[2]*wq[1][2]+P_##1[3]*wq[1][3]; \
            acc += P_##2[0]*wq[2][0]+P_##2[1]*wq[2][1]+P_##2[2]*wq[2][2]+P_##2[3]*wq[2][3]; \
            acc += P_##3[0]*wq[3][0]+P_##3[1]*wq[3][1]+P_##3[2]*wq[3][2]+P_##3[3]*wq[3][3]; \
            acc += P_##4[0]*wq[4][0]+P_##4[1]*wq[4][1]+P_##4[2]*wq[4][2]+P_##4[3]*wq[4][3]; \
            acc += P_##5[0]*wq[5][0]+P_##5[1]*wq[5][1]+P_##5[2]*wq[5][2]+P_##5[3]*wq[5][3]; \
            acc += P_##6[0]*wq[6][0]+P_##6[1]*wq[6][1]+P_##6[2]*wq[6][2]+P_##6[3]*wq[6][3]; \
            acc += P_##7[0]*wq[7][0]+P_##7[1]*wq[7][1]+P_##7[2]*wq[7][2]+P_##7[3]*wq[7][3]; \
            acc += P_##8[0]*wq[8][0]+P_##8[1]*wq[8][1]+P_##8[2]*wq[8][2]+P_##8[3]*wq[8][3]; \
            acc += P_##9[0]*wq[9][0]+P_##9[1]*wq[9][1]+P_##9[2]*wq[9][2]+P_##9[3]*wq[9][3]; \
            acc += P_##10[0]*wq[10][0]+P_##10[1]*wq[10][1]+P_##10[2]*wq[10][2]+P_##10[3]*wq[10][3]; \
            acc += P_##11[0]*wq[11][0]+P_##11[1]*wq[11][1]+P_##11[2]*wq[11][2]+P_##11[3]*wq[11][3]; \
            acc += P_##12[0]*wq[12][0]+P_##12[1]*wq[12][1]+P_##12[2]*wq[12][2]+P_##12[3]*wq[12][3]; \
            acc += P_##13[0]*wq[13][0]+P_##13[1]*wq[13][1]+P_##13[2]*wq[13][2]+P_##13[3]*wq[13][3]; \
            acc += P_##14[0]*wq[14][0]+P_##14[1]*wq[14][1]+P_##14[2]*wq[14][2]+P_##14[3]*wq[14][3]; \
            acc += P_##15[0]*wq[15][0]+P_##15[1]*wq[15][1]+P_##15[2]*wq[15][2]+P_##15[3]*wq[15][3]; } while (0)
        ISSUE_BANK(A, (zp));          // bt0
        ISSUE_BANK(B, (zp + 64));     // bt1
        WAITV(16); DOT_BANK(A, owp);
        ISSUE_BANK(A, (zp + 128));    // bt2
        WAITV(16); DOT_BANK(B, owp + 64);
        ISSUE_BANK(B, (zp + 192));    // bt3
        WAITV(16); DOT_BANK(A, owp + 128);
        WAITV(0);  DOT_BANK(B, owp + 192);
        #undef ISSUE_BANK
        #undef DOT_BANK
        acc += __shfl_xor(acc, 16, 64);
        acc += __shfl_xor(acc, 32, 64);
        if (kq == 0)
            p.out[(size_t)ty * BBATCH * OOUT + bb * OOUT + oo] = acc + p.out_b[oo];
    };

    __syncthreads();              // Ulds staged before wave-6 use
    if (wave == 6) uxcomp(0);     // EX ux parity-0 for step 0

    // pre-loop barrier (gen 1): act init + EX[6] visible
    __syncthreads();
    if (tid == 0) { arrive(); waitbar(64u); }
    __syncthreads();

    for (int t = 0; t < TT; ++t) {
        const int rp = (t + 1) & 1;  // read parity (acts of state t-1)
        const int wp = t & 1;        // write parity (acts of state t)

        if (wave < 6) {
            // waves 0..5: mats r/i/tau, each split into two K-halves
            const int mat = wave >> 1, half = wave & 1;
            const int m = lane & 15, kb = lane >> 4, sw = m & 7;
            const unsigned short* ap = p.act + (mat * 2 + rp) * BBATCH * HH
                                       + (b0 + m) * HH + half * 512 + kb * 8;
            bfrag a0,a1,a2,a3,a4,a5,a6,a7,a8,a9,a10,a11,a12,a13,a14,a15;
            LDC(a0,ap,0);    LDC(a1,ap,64);   LDC(a2,ap,128);  LDC(a3,ap,192);
            LDC(a4,ap,256);  LDC(a5,ap,320);  LDC(a6,ap,384);  LDC(a7,ap,448);
            LDC(a8,ap,512);  LDC(a9,ap,576);  LDC(a10,ap,640); LDC(a11,ap,704);
            LDC(a12,ap,768); LDC(a13,ap,832); LDC(a14,ap,896); LDC(a15,ap,960);
            f32x4 acc = {0.f, 0.f, 0.f, 0.f};
            const unsigned short* wrow = Wlds + (mat * 16 + m) * 1024;
            #define STW(ks_, av_) acc = MFMA(av_, *(const bfrag*)(wrow + \
                ((((half << 6) + ((ks_) << 2) + kb) ^ sw) << 3)), acc);
            WAITV(8);
            STW(0,a0) STW(1,a1) STW(2,a2) STW(3,a3)
            STW(4,a4) STW(5,a5) STW(6,a6) STW(7,a7)
            WAITV(0);
            STW(8,a8) STW(9,a9) STW(10,a10) STW(11,a11)
            STW(12,a12) STW(13,a13) STW(14,a14) STW(15,a15)
            #undef STW
            #pragma unroll
            for (int q = 0; q < 4; ++q)
                EX[wave * 256 + (kb * 4 + q) * 16 + m] = acc[q];  // row=(lane>>4)*4+q, col=m
        }
        // waves 6,7: idle in compute phase (their work is in the barrier window)

        __syncthreads();

        if (tid < 256) {
            const float mr = EX[0 * 256 + tid] + EX[1 * 256 + tid];
            const float mi = EX[2 * 256 + tid] + EX[3 * 256 + tid];
            const float mt = EX[4 * 256 + tid] + EX[5 * 256 + tid];
            const float ux = EX[(6 + (t & 1)) * 256 + tid] + cub;
            const float dr0 = -zr + mr + ux + cbr;
            const float di0 = -zi + mi + ux + cbi;
            float tau = sigm(mt + cwtb) + ctb;
            tau = fminf(fmaxf(tau, 0.01f), 1.0f) + 1e-6f;
            const float dzr = fminf(fmaxf(dr0 / tau, -10.f), 10.f);
            const float dzi = fminf(fmaxf(di0 / tau, -10.f), 10.f);
            zr = fminf(fmaxf(zr + 0.1f * dzr, -100.f), 100.f);
            zi = fminf(fmaxf(zi + 0.1f * dzi, -100.f), 100.f);
            const float ar = tanh_fast(zr), ai = tanh_fast(zi);
            const float zm = sqrtf(zr * zr + zi * zi + 1e-20f);
            STC(p.act + (0 * 2 + wp) * BBATCH * HH + myoff, f2bf(ar));
            STC(p.act + (1 * 2 + wp) * BBATCH * HH + myoff, f2bf(ai));
            STC(p.act + (2 * 2 + wp) * BBATCH * HH + myoff, f2bf(zm));
            STC(p.zread + wp * BBATCH * HH + myoff, zr);
        }

        __syncthreads();                           // drains stores to LLC
        if (tid == 0) arrive();
        if (wave == 6 && t + 1 < TT) uxcomp(t + 1);  // hidden under barrier wait
        if (wave == 7 && t >= 1) readout(t - 1);     // hidden under barrier wait
        if (tid == 0) waitbar(64u * (t + 2));
        __syncthreads();
    }

    if (wave == 7) readout(TT - 1);
}

extern "C" void kernel_launch(void* const* d_in, const int* in_sizes, int n_in,
                              void* d_out, int out_size, void* d_ws, size_t ws_size,
                              hipStream_t stream) {
    Params p;
    p.x         = (const float*)d_in[0];
    p.W_real    = (const float*)d_in[1];
    p.W_imag    = (const float*)d_in[2];
    p.U_w       = (const float*)d_in[3];
    p.U_b       = (const float*)d_in[4];
    p.W_tau_w   = (const float*)d_in[5];
    p.W_tau_b   = (const float*)d_in[6];
    p.mask_real = (const float*)d_in[7];
    p.mask_imag = (const float*)d_in[8];
    p.tau_bias  = (const float*)d_in[9];
    p.b_real    = (const float*)d_in[10];
    p.b_imag    = (const float*)d_in[11];
    p.out_w     = (const float*)d_in[12];
    p.out_b     = (const float*)d_in[13];
    p.out   = (float*)d_out;
    p.act   = (unsigned short*)d_ws;                          // 786432 B
    p.zread = (float*)((char*)d_ws + 786432);                 // 524288 B
    p.bar   = (unsigned int*)((char*)d_ws + 1310720);         // 512 B

    hipMemsetAsync((char*)d_ws + 1310720, 0, 512, stream);    // reset barrier counters

    constexpr unsigned smem = 3 * 16 * 1024 * 2 + 16 * 256 * 2 + 8 * 256 * 4; // 114688 B
    hipFuncSetAttribute(reinterpret_cast<const void*>(lnn_fused),
                        hipFuncAttributeMaxDynamicSharedMemorySize, smem);
    void* args[] = { &p };
    hipLaunchCooperativeKernel(reinterpret_cast<const void*>(lnn_fused),
                               dim3(256), dim3(512), args, smem, stream);
}